// Round 9
// baseline (1320.533 us; speedup 1.0000x reference)
//
#include <hip/hip_runtime.h>
#include <hip/hip_bf16.h>

// QwenMoe: T=1024 H=2048 I=1408 E=60 SI=5632 topk=4, fp32 in/out.
// R9: R8 (reg-streaming flatmm, no LDS/no barriers, counted vmcnt) with
// crash fixes: (a) __launch_bounds__(256,2) on both GEMMs so staging regs
// never spill (pending-async dst spill was the R8 fault), (b) ext-vector
// asm operands (HIP float4/uint4 are structs -> bad "v" operands).

typedef float  f32x4  __attribute__((ext_vector_type(4)));
typedef unsigned int u32x4 __attribute__((ext_vector_type(4)));
typedef short  bf16x8 __attribute__((ext_vector_type(8)));
typedef unsigned short u16;
typedef unsigned int   u32;

constexpr int TT = 1024, HD = 2048, ID = 1408, NE = 60, SID = 5632, KTOP = 4;
constexpr int NBR_GU = (ID / 64) * NE;                     // 1320 routed gu blocks
constexpr int NB_GU  = NBR_GU + (SID / 64) * (TT / 128);   // +704 shared = 2024
constexpr int NBS_DN = (HD / 64) * (TT / 128);             // 256 shared down blocks
constexpr int NB_DN  = NBS_DN + (HD / 64) * NE;            // +1920 routed = 2176

#define GL4(dst, ptr) asm volatile("global_load_dwordx4 %0, %1, off" : "=&v"(dst) : "v"(ptr))
#define WAITVM(n) do { asm volatile("s_waitcnt vmcnt(" #n ")" ::: "memory"); \
                       __builtin_amdgcn_sched_barrier(0); } while (0)

__device__ __forceinline__ u16 f2bf(float f) {
    union { float f; u32 u; } v; v.f = f;
    u32 r = v.u + 0x7FFFu + ((v.u >> 16) & 1u);   // RNE
    return (u16)(r >> 16);
}
__device__ __forceinline__ u32 cvtpk(float a, float b) {
    u32 r; asm("v_cvt_pk_bf16_f32 %0, %1, %2" : "=v"(r) : "v"(a), "v"(b));
    return r;
}
__device__ __forceinline__ bf16x8 cvt8(f32x4 a, f32x4 b) {
    union { u32 u[4]; bf16x8 v; } rr;
    rr.u[0] = cvtpk(a[0], a[1]); rr.u[1] = cvtpk(a[2], a[3]);
    rr.u[2] = cvtpk(b[0], b[1]); rr.u[3] = cvtpk(b[2], b[3]);
    return rr.v;
}
__device__ __forceinline__ bf16x8 asbf(u32x4 v) {
    union { u32x4 u; bf16x8 b; } c; c.u = v; return c.b;
}

// ---------------- tiny utility kernels ----------------
__global__ void zero_k(int* __restrict__ p) { p[threadIdx.x] = 0; }

__global__ __launch_bounds__(256) void zeroout_k(float* __restrict__ p) {
    ((float4*)p)[blockIdx.x * 256 + threadIdx.x] = make_float4(0.f, 0.f, 0.f, 0.f);
}

__global__ __launch_bounds__(256) void xcvt_k(const float* __restrict__ x, u16* __restrict__ xb)
{
    size_t i = ((size_t)blockIdx.x * 256 + threadIdx.x) * 16;
    const float4* p = (const float4*)(x + i);
    float4 f0 = p[0], f1 = p[1], f2 = p[2], f3 = p[3];
    uint4 o0, o1;
    o0.x = cvtpk(f0.x, f0.y); o0.y = cvtpk(f0.z, f0.w);
    o0.z = cvtpk(f1.x, f1.y); o0.w = cvtpk(f1.z, f1.w);
    o1.x = cvtpk(f2.x, f2.y); o1.y = cvtpk(f2.z, f2.w);
    o1.z = cvtpk(f3.x, f3.y); o1.w = cvtpk(f3.z, f3.w);
    ((uint4*)(xb + i))[0] = o0;
    ((uint4*)(xb + i))[1] = o1;
}

// ---------------- router ----------------
__global__ __launch_bounds__(64) void router_k(
    const float* __restrict__ x, const float* __restrict__ rw,
    const float* __restrict__ sgw,
    float* __restrict__ topk_p, int* __restrict__ topk_i,
    int* __restrict__ cnt, float* __restrict__ sgate)
{
    const int t = blockIdx.x, l = threadIdx.x;
    const float4* xr = ((const float4*)(x + (size_t)t * HD)) + l * 8;
    float4 xa[8];
    #pragma unroll
    for (int i = 0; i < 8; i++) xa[i] = xr[i];

    float le = 0.f;
    for (int e = 0; e < NE; e++) {
        const float4* wr = ((const float4*)(rw + (size_t)e * HD)) + l * 8;
        float a = 0.f;
        #pragma unroll
        for (int i = 0; i < 8; i++) {
            float4 wv = wr[i];
            a += xa[i].x * wv.x + xa[i].y * wv.y + xa[i].z * wv.z + xa[i].w * wv.w;
        }
        #pragma unroll
        for (int s = 32; s; s >>= 1) a += __shfl_xor(a, s);
        if (l == e) le = a;
    }
    {
        const float4* wr = ((const float4*)sgw) + l * 8;
        float a = 0.f;
        #pragma unroll
        for (int i = 0; i < 8; i++) {
            float4 wv = wr[i];
            a += xa[i].x * wv.x + xa[i].y * wv.y + xa[i].z * wv.z + xa[i].w * wv.w;
        }
        #pragma unroll
        for (int s = 32; s; s >>= 1) a += __shfl_xor(a, s);
        if (l == 0) sgate[t] = 1.f / (1.f + __expf(-a));
    }
    float mv = (l < NE) ? le : -3.4e38f;
    #pragma unroll
    for (int s = 32; s; s >>= 1) mv = fmaxf(mv, __shfl_xor(mv, s));
    float p = (l < NE) ? __expf(le - mv) : 0.f;
    float ss = p;
    #pragma unroll
    for (int s = 32; s; s >>= 1) ss += __shfl_xor(ss, s);
    p /= ss;
    float pv = (l < NE) ? p : -1.f;
    int   pi = l;
    float kp = 0.f; int ki = 0;
    for (int k = 0; k < KTOP; k++) {
        float bv = pv; int bi = pi;
        #pragma unroll
        for (int s = 32; s; s >>= 1) {
            float ov = __shfl_xor(bv, s); int oi = __shfl_xor(bi, s);
            if (ov > bv || (ov == bv && oi < bi)) { bv = ov; bi = oi; }
        }
        if (l == k) { kp = bv; ki = bi; }
        if (pi == bi) pv = -1.f;
    }
    if (l < KTOP) {
        topk_p[t * KTOP + l] = kp;
        topk_i[t * KTOP + l] = ki;
        atomicAdd(&cnt[ki], 1);
    }
}

__global__ __launch_bounds__(64) void prefix_k(const int* __restrict__ cnt, int* __restrict__ base)
{
    int l = threadIdx.x;
    if (l < NE) {
        int s = 0;
        for (int j = 0; j < l; j++) s += cnt[j];
        base[l] = s;
    }
}

__global__ __launch_bounds__(256) void scatter_k(
    const float* __restrict__ topk_p, const int* __restrict__ topk_i,
    const int* __restrict__ base, int* __restrict__ fill,
    int* __restrict__ slot_tok, float* __restrict__ slot_wt)
{
    int t = blockIdx.x * blockDim.x + threadIdx.x;
    if (t >= TT) return;
    for (int k = 0; k < KTOP; k++) {
        int e = topk_i[t * KTOP + k];
        int pos = atomicAdd(&fill[e], 1);
        int s = base[e] + pos;
        slot_tok[s] = t;
        slot_wt[s]  = topk_p[t * KTOP + k];
    }
}

// ======== fused GU, reg-streaming: routed (bid<1320) + shared.
// Block 128M x 64N, 4 waves (2M x 2N), wave 64M x 32N. 12 loads/phase.
__global__ __launch_bounds__(256, 2) void gu_all(
    const u16* __restrict__ Xb,
    const float* __restrict__ w_gate, const float* __restrict__ w_up,
    const float* __restrict__ sw_g, const float* __restrict__ sw_u,
    u16* __restrict__ h, u16* __restrict__ hs,
    const int* __restrict__ slot_tok, const float* __restrict__ slot_wt,
    const int* __restrict__ cnt, const int* __restrict__ basea)
{
    const int bid = blockIdx.x;
    const bool grouped = bid < NBR_GU;
    const int tid = threadIdx.x, w = tid >> 6, lane = tid & 63;
    const int lm = lane & 15, lk = lane >> 4;
    const int wm0 = (w >> 1) * 64, wn0 = (w & 1) * 32;

    int e = 0, my = 0, nb;
    const float *Wg, *Wu; u16* Hout; int Nout;
    if (grouped) {
        e = bid / 22; nb = bid % 22;
        Wg = w_gate + (size_t)e * ID * HD; Wu = w_up + (size_t)e * ID * HD;
        Hout = h; Nout = ID;
    } else {
        int sid = bid - NBR_GU; my = sid / 88; nb = sid % 88;
        Wg = sw_g; Wu = sw_u; Hout = hs; Nout = SID;
    }
    const int mcnt  = grouped ? cnt[e] : 128;
    const int mbase = grouped ? basea[e] : 0;
    const int nk = HD >> 5;   // 64 K-steps

    for (int mt = 0; grouped ? (mt * 128 < mcnt) : (mt == 0); ++mt) {
        // per-lane A fragment row pointers (phase0 at k=0, phase1 at k=32)
        const u16* pa0[4]; const u16* pa1[4];
        #pragma unroll
        for (int mf = 0; mf < 4; mf++) {
            int mrow = wm0 + mf * 16 + lm;
            int row;
            if (grouped) {
                int sl = mbase + mt * 128 + mrow;
                row = (mt * 128 + mrow < mcnt) ? slot_tok[sl] : slot_tok[mbase];
            } else row = my * 128 + mrow;
            pa0[mf] = Xb + (size_t)row * HD + lk * 8;
            pa1[mf] = pa0[mf] + 32;
        }
        // per-lane B fragment row pointers
        const float *pg0[2], *pg1[2], *pu0[2], *pu1[2];
        #pragma unroll
        for (int nf = 0; nf < 2; nf++) {
            size_t row = (size_t)(nb * 64 + wn0 + nf * 16 + lm);
            pg0[nf] = Wg + row * HD + lk * 8; pg1[nf] = pg0[nf] + 32;
            pu0[nf] = Wu + row * HD + lk * 8; pu1[nf] = pu0[nf] + 32;
        }

        f32x4 accG[4][2], accU[4][2];
        #pragma unroll
        for (int mf = 0; mf < 4; mf++)
            #pragma unroll
            for (int nf = 0; nf < 2; nf++) {
                accG[mf][nf] = f32x4{0.f, 0.f, 0.f, 0.f};
                accU[mf][nf] = f32x4{0.f, 0.f, 0.f, 0.f};
            }

        u32x4 A0[4], A1[4];
        f32x4 G0[4], G1[4], U0[4], U1[4];

#define LOADP(A_, G_, U_, PA_, PG_, PU_) do {                                  \
        GL4(A_[0], PA_[0]); GL4(A_[1], PA_[1]);                                \
        GL4(A_[2], PA_[2]); GL4(A_[3], PA_[3]);                                \
        GL4(G_[0], PG_[0]); GL4(G_[1], PG_[0] + 4);                            \
        GL4(G_[2], PG_[1]); GL4(G_[3], PG_[1] + 4);                            \
        GL4(U_[0], PU_[0]); GL4(U_[1], PU_[0] + 4);                            \
        GL4(U_[2], PU_[1]); GL4(U_[3], PU_[1] + 4);                            \
        PA_[0] += 64; PA_[1] += 64; PA_[2] += 64; PA_[3] += 64;                \
        PG_[0] += 64; PG_[1] += 64; PU_[0] += 64; PU_[1] += 64;                \
    } while (0)

#define COMPP(A_, G_, U_) do {                                                 \
        bf16x8 bg0 = cvt8(G_[0], G_[1]), bg1 = cvt8(G_[2], G_[3]);             \
        bf16x8 bu0 = cvt8(U_[0], U_[1]), bu1 = cvt8(U_[2], U_[3]);             \
        _Pragma("unroll")                                                      \
        for (int mf = 0; mf < 4; mf++) {                                       \
            bf16x8 af = asbf(A_[mf]);                                          \
            accG[mf][0] = __builtin_amdgcn_mfma_f32_16x16x32_bf16(af, bg0, accG[mf][0], 0, 0, 0); \
            accG[mf][1] = __builtin_amdgcn_mfma_f32_16x16x32_bf16(af, bg1, accG[mf][1], 0, 0, 0); \
            accU[mf][0] = __builtin_amdgcn_mfma_f32_16x16x32_bf16(af, bu0, accU[mf][0], 0, 0, 0); \
            accU[mf][1] = __builtin_amdgcn_mfma_f32_16x16x32_bf16(af, bu1, accU[mf][1], 0, 0, 0); \
        }                                                                      \
    } while (0)

        LOADP(A0, G0, U0, pa0, pg0, pu0);                 // phase k=0
        for (int t = 0; t + 2 < nk; t += 2) {
            LOADP(A1, G1, U1, pa1, pg1, pu1);             // k=t+1
            WAITVM(12); COMPP(A0, G0, U0);
            LOADP(A0, G0, U0, pa0, pg0, pu0);             // k=t+2
            WAITVM(12); COMPP(A1, G1, U1);
        }
        LOADP(A1, G1, U1, pa1, pg1, pu1);                 // k=nk-1
        WAITVM(12); COMPP(A0, G0, U0);
        WAITVM(0);  COMPP(A1, G1, U1);
#undef LOADP
#undef COMPP

        // epilogue: silu(g)*u*wt -> bf16. D: col=lane&15, row=(lane>>4)*4+reg
        #pragma unroll
        for (int mf = 0; mf < 4; mf++)
            #pragma unroll
            for (int j = 0; j < 4; j++) {
                int m = wm0 + mf * 16 + lk * 4 + j;
                bool valid = grouped ? (mt * 128 + m < mcnt) : true;
                if (valid) {
                    size_t row; float wt;
                    if (grouped) {
                        size_t sl = (size_t)(mbase + mt * 128 + m);
                        row = sl; wt = slot_wt[sl];
                    } else { row = (size_t)(my * 128 + m); wt = 1.f; }
                    #pragma unroll
                    for (int nf = 0; nf < 2; nf++) {
                        int col = nb * 64 + wn0 + nf * 16 + lm;
                        float g = accG[mf][nf][j], u = accU[mf][nf][j];
                        float hv = g / (1.f + __expf(-g)) * u * wt;
                        Hout[row * (size_t)Nout + col] = f2bf(hv);
                    }
                }
            }
    }
}

// ======== fused DOWN, reg-streaming: shared (bid<256, K=5632) + routed (K=1408).
// All-atomicAdd onto pre-zeroed out. 8 loads/phase.
__global__ __launch_bounds__(256, 2) void down_all(
    const u16* __restrict__ h, const u16* __restrict__ hs,
    const float* __restrict__ w_down, const float* __restrict__ sw_d,
    float* __restrict__ outF,
    const int* __restrict__ slot_tok, const float* __restrict__ sgate,
    const int* __restrict__ cnt, const int* __restrict__ basea)
{
    const int bid = blockIdx.x;
    const bool shared_m = bid < NBS_DN;
    const int tid = threadIdx.x, w = tid >> 6, lane = tid & 63;
    const int lm = lane & 15, lk = lane >> 4;
    const int wm0 = (w >> 1) * 64, wn0 = (w & 1) * 32;

    int e = 0, my = 0, nb, K;
    const u16* Ap; const float* Wp;
    if (shared_m) {
        my = bid / 32; nb = bid % 32; K = SID; Ap = hs; Wp = sw_d;
    } else {
        int rid = bid - NBS_DN; e = rid / 32; nb = rid % 32; K = ID;
        Ap = h; Wp = w_down + (size_t)e * HD * ID;
    }
    const int mcnt  = shared_m ? 128 : cnt[e];
    const int mbase = shared_m ? 0 : basea[e];
    const int nk = K >> 5;   // 176 shared, 44 routed (both even)

    for (int mt = 0; shared_m ? (mt == 0) : (mt * 128 < mcnt); ++mt) {
        const u16* pa0[4]; const u16* pa1[4];
        #pragma unroll
        for (int mf = 0; mf < 4; mf++) {
            int mrow = wm0 + mf * 16 + lm;
            size_t row = shared_m ? (size_t)(my * 128 + mrow)
                                  : (size_t)(mbase + mt * 128 + mrow);  // h padded
            pa0[mf] = Ap + row * K + lk * 8;
            pa1[mf] = pa0[mf] + 32;
        }
        const float *pb0[2], *pb1[2];
        #pragma unroll
        for (int nf = 0; nf < 2; nf++) {
            size_t row = (size_t)(nb * 64 + wn0 + nf * 16 + lm);
            pb0[nf] = Wp + row * K + lk * 8; pb1[nf] = pb0[nf] + 32;
        }

        f32x4 acc[4][2];
        #pragma unroll
        for (int mf = 0; mf < 4; mf++)
            #pragma unroll
            for (int nf = 0; nf < 2; nf++) acc[mf][nf] = f32x4{0.f, 0.f, 0.f, 0.f};

        u32x4 A0[4], A1[4];
        f32x4 B0[4], B1[4];

#define LOADP(A_, B_, PA_, PB_) do {                                           \
        GL4(A_[0], PA_[0]); GL4(A_[1], PA_[1]);                                \
        GL4(A_[2], PA_[2]); GL4(A_[3], PA_[3]);                                \
        GL4(B_[0], PB_[0]); GL4(B_[1], PB_[0] + 4);                            \
        GL4(B_[2], PB_[1]); GL4(B_[3], PB_[1] + 4);                            \
        PA_[0] += 64; PA_[1] += 64; PA_[2] += 64; PA_[3] += 64;                \
        PB_[0] += 64; PB_[1] += 64;                                            \
    } while (0)

#define COMPP(A_, B_) do {                                                     \
        bf16x8 b0 = cvt8(B_[0], B_[1]), b1 = cvt8(B_[2], B_[3]);               \
        _Pragma("unroll")                                                      \
        for (int mf = 0; mf < 4; mf++) {                                       \
            bf16x8 af = asbf(A_[mf]);                                          \
            acc[mf][0] = __builtin_amdgcn_mfma_f32_16x16x32_bf16(af, b0, acc[mf][0], 0, 0, 0); \
            acc[mf][1] = __builtin_amdgcn_mfma_f32_16x16x32_bf16(af, b1, acc[mf][1], 0, 0, 0); \
        }                                                                      \
    } while (0)

        LOADP(A0, B0, pa0, pb0);                          // k=0
        for (int t = 0; t + 2 < nk; t += 2) {
            LOADP(A1, B1, pa1, pb1);                      // k=t+1
            WAITVM(8); COMPP(A0, B0);
            LOADP(A0, B0, pa0, pb0);                      // k=t+2
            WAITVM(8); COMPP(A1, B1);
        }
        LOADP(A1, B1, pa1, pb1);                          // k=nk-1
        WAITVM(8); COMPP(A0, B0);
        WAITVM(0); COMPP(A1, B1);
#undef LOADP
#undef COMPP

        #pragma unroll
        for (int mf = 0; mf < 4; mf++)
            #pragma unroll
            for (int j = 0; j < 4; j++) {
                int m = wm0 + mf * 16 + lk * 4 + j;
                if (mt * 128 + m < mcnt) {
                    int tok; float scale;
                    if (shared_m) { tok = my * 128 + m; scale = sgate[tok]; }
                    else          { tok = slot_tok[mbase + mt * 128 + m]; scale = 1.f; }
                    #pragma unroll
                    for (int nf = 0; nf < 2; nf++) {
                        int col = nb * 64 + wn0 + nf * 16 + lm;
                        atomicAdd(&outF[(size_t)tok * HD + col], scale * acc[mf][nf][j]);
                    }
                }
            }
    }
}

extern "C" void kernel_launch(void* const* d_in, const int* in_sizes, int n_in,
                              void* d_out, int out_size, void* d_ws, size_t ws_size,
                              hipStream_t stream)
{
    const float* x      = (const float*)d_in[0];
    const float* rw     = (const float*)d_in[1];
    const float* w_gate = (const float*)d_in[2];
    const float* w_up   = (const float*)d_in[3];
    const float* w_down = (const float*)d_in[4];
    const float* sw_g   = (const float*)d_in[5];
    const float* sw_u   = (const float*)d_in[6];
    const float* sw_d   = (const float*)d_in[7];
    const float* sgw    = (const float*)d_in[8];
    float* out = (float*)d_out;

    char* ws = (char*)d_ws;
    int*   cnt      = (int*)(ws + 0);
    int*   fill     = (int*)(ws + 256);
    int*   basea    = (int*)(ws + 512);
    float* sgate    = (float*)(ws + 768);
    float* topk_p   = (float*)(ws + 5120);
    int*   topk_i   = (int*)(ws + 21504);
    int*   slot_tok = (int*)(ws + 37888);
    float* slot_wt  = (float*)(ws + 54272);
    u16*   xb = (u16*)(ws + 71680);              // [1024][2048] bf16
    u16*   h  = xb + (size_t)TT * HD;            // [4096+128][1408] bf16 (padded)
    u16*   hs = h + (size_t)(4096 + 128) * ID;   // [1024][5632] bf16

    zero_k<<<1, 128, 0, stream>>>(cnt);                       // cnt + fill
    zeroout_k<<<TT * HD / 1024, 256, 0, stream>>>(out);       // 8.4 MB fast zero
    xcvt_k<<<512, 256, 0, stream>>>(x, xb);
    router_k<<<TT, 64, 0, stream>>>(x, rw, sgw, topk_p, topk_i, cnt, sgate);
    prefix_k<<<1, 64, 0, stream>>>(cnt, basea);
    scatter_k<<<4, 256, 0, stream>>>(topk_p, topk_i, basea, fill, slot_tok, slot_wt);

    gu_all<<<NB_GU, 256, 0, stream>>>(
        xb, w_gate, w_up, sw_g, sw_u, h, hs,
        slot_tok, slot_wt, cnt, basea);

    down_all<<<NB_DN, 256, 0, stream>>>(
        h, hs, w_down, sw_d, out,
        slot_tok, sgate, cnt, basea);
}

// Round 11
// 781.847 us; speedup vs baseline: 1.6890x; 1.6890x over previous
//
#include <hip/hip_runtime.h>
#include <hip/hip_bf16.h>

// QwenMoe: T=1024 H=2048 I=1408 E=60 SI=5632 topk=4, fp32 in/out.
// R11 = R10 + rule #18 fix: WAITVM carries sched_barrier(0) so cvt_pk of
// GL4-loaded regs cannot be hoisted above the vmcnt wait (R10's corruption).
// Structure: A via GLDS bf16 4-buf depth-2; B via T14 reg-stage fp32 ->
// cvt_pk -> bf16 ds_write (2-buf, issued depth-2); one lgkm+barrier per
// K-step; x4-unrolled with named reg sets; counted vmcnt(6)/(4).

typedef float  f32x4  __attribute__((ext_vector_type(4)));
typedef short  bf16x8 __attribute__((ext_vector_type(8)));
typedef unsigned short u16;
typedef unsigned int   u32;

constexpr int TT = 1024, HD = 2048, ID = 1408, NE = 60, SID = 5632, KTOP = 4;
constexpr int NBR_GU = (ID / 64) * NE;                     // 1320 routed gu blocks
constexpr int NB_GU  = NBR_GU + (SID / 64) * (TT / 128);   // +704 shared = 2024
constexpr int NBS_DN = (HD / 64) * (TT / 128);             // 256 shared down blocks
constexpr int NB_DN  = NBS_DN + (HD / 64) * NE;            // +1920 routed = 2176

#define GLDS(g, l) __builtin_amdgcn_global_load_lds( \
    (const __attribute__((address_space(1))) void*)(g), \
    (__attribute__((address_space(3))) void*)(l), 16, 0, 0)
#define GL4(dst, ptr) asm volatile("global_load_dwordx4 %0, %1, off" : "=&v"(dst) : "v"(ptr))
#define WAITVM(n) do { asm volatile("s_waitcnt vmcnt(" #n ")" ::: "memory"); \
                       __builtin_amdgcn_sched_barrier(0); } while (0)
#define LGKMBAR() do { asm volatile("s_waitcnt lgkmcnt(0)" ::: "memory"); \
    __builtin_amdgcn_s_barrier(); \
    asm volatile("" ::: "memory"); } while (0)

__device__ __forceinline__ u16 f2bf(float f) {
    union { float f; u32 u; } v; v.f = f;
    u32 r = v.u + 0x7FFFu + ((v.u >> 16) & 1u);   // RNE
    return (u16)(r >> 16);
}
__device__ __forceinline__ u32 cvtpk(float a, float b) {
    u32 r; asm("v_cvt_pk_bf16_f32 %0, %1, %2" : "=v"(r) : "v"(a), "v"(b));
    return r;
}
__device__ __forceinline__ bf16x8 cvt8(f32x4 a, f32x4 b) {
    union { u32 u[4]; bf16x8 v; } rr;
    rr.u[0] = cvtpk(a[0], a[1]); rr.u[1] = cvtpk(a[2], a[3]);
    rr.u[2] = cvtpk(b[0], b[1]); rr.u[3] = cvtpk(b[2], b[3]);
    return rr.v;
}

// ---------------- tiny utility kernels ----------------
__global__ void zero_k(int* __restrict__ p) { p[threadIdx.x] = 0; }

__global__ __launch_bounds__(256) void zeroout_k(float* __restrict__ p) {
    ((float4*)p)[blockIdx.x * 256 + threadIdx.x] = make_float4(0.f, 0.f, 0.f, 0.f);
}

__global__ __launch_bounds__(256) void xcvt_k(const float* __restrict__ x, u16* __restrict__ xb)
{
    size_t i = ((size_t)blockIdx.x * 256 + threadIdx.x) * 16;
    const float4* p = (const float4*)(x + i);
    float4 f0 = p[0], f1 = p[1], f2 = p[2], f3 = p[3];
    uint4 o0, o1;
    o0.x = cvtpk(f0.x, f0.y); o0.y = cvtpk(f0.z, f0.w);
    o0.z = cvtpk(f1.x, f1.y); o0.w = cvtpk(f1.z, f1.w);
    o1.x = cvtpk(f2.x, f2.y); o1.y = cvtpk(f2.z, f2.w);
    o1.z = cvtpk(f3.x, f3.y); o1.w = cvtpk(f3.z, f3.w);
    ((uint4*)(xb + i))[0] = o0;
    ((uint4*)(xb + i))[1] = o1;
}

// ---------------- router ----------------
__global__ __launch_bounds__(64) void router_k(
    const float* __restrict__ x, const float* __restrict__ rw,
    const float* __restrict__ sgw,
    float* __restrict__ topk_p, int* __restrict__ topk_i,
    int* __restrict__ cnt, float* __restrict__ sgate)
{
    const int t = blockIdx.x, l = threadIdx.x;
    const float4* xr = ((const float4*)(x + (size_t)t * HD)) + l * 8;
    float4 xa[8];
    #pragma unroll
    for (int i = 0; i < 8; i++) xa[i] = xr[i];

    float le = 0.f;
    for (int e = 0; e < NE; e++) {
        const float4* wr = ((const float4*)(rw + (size_t)e * HD)) + l * 8;
        float a = 0.f;
        #pragma unroll
        for (int i = 0; i < 8; i++) {
            float4 wv = wr[i];
            a += xa[i].x * wv.x + xa[i].y * wv.y + xa[i].z * wv.z + xa[i].w * wv.w;
        }
        #pragma unroll
        for (int s = 32; s; s >>= 1) a += __shfl_xor(a, s);
        if (l == e) le = a;
    }
    {
        const float4* wr = ((const float4*)sgw) + l * 8;
        float a = 0.f;
        #pragma unroll
        for (int i = 0; i < 8; i++) {
            float4 wv = wr[i];
            a += xa[i].x * wv.x + xa[i].y * wv.y + xa[i].z * wv.z + xa[i].w * wv.w;
        }
        #pragma unroll
        for (int s = 32; s; s >>= 1) a += __shfl_xor(a, s);
        if (l == 0) sgate[t] = 1.f / (1.f + __expf(-a));
    }
    float mv = (l < NE) ? le : -3.4e38f;
    #pragma unroll
    for (int s = 32; s; s >>= 1) mv = fmaxf(mv, __shfl_xor(mv, s));
    float p = (l < NE) ? __expf(le - mv) : 0.f;
    float ss = p;
    #pragma unroll
    for (int s = 32; s; s >>= 1) ss += __shfl_xor(ss, s);
    p /= ss;
    float pv = (l < NE) ? p : -1.f;
    int   pi = l;
    float kp = 0.f; int ki = 0;
    for (int k = 0; k < KTOP; k++) {
        float bv = pv; int bi = pi;
        #pragma unroll
        for (int s = 32; s; s >>= 1) {
            float ov = __shfl_xor(bv, s); int oi = __shfl_xor(bi, s);
            if (ov > bv || (ov == bv && oi < bi)) { bv = ov; bi = oi; }
        }
        if (l == k) { kp = bv; ki = bi; }
        if (pi == bi) pv = -1.f;
    }
    if (l < KTOP) {
        topk_p[t * KTOP + l] = kp;
        topk_i[t * KTOP + l] = ki;
        atomicAdd(&cnt[ki], 1);
    }
}

__global__ __launch_bounds__(64) void prefix_k(const int* __restrict__ cnt, int* __restrict__ base)
{
    int l = threadIdx.x;
    if (l < NE) {
        int s = 0;
        for (int j = 0; j < l; j++) s += cnt[j];
        base[l] = s;
    }
}

__global__ __launch_bounds__(256) void scatter_k(
    const float* __restrict__ topk_p, const int* __restrict__ topk_i,
    const int* __restrict__ base, int* __restrict__ fill,
    int* __restrict__ slot_tok, float* __restrict__ slot_wt)
{
    int t = blockIdx.x * blockDim.x + threadIdx.x;
    if (t >= TT) return;
    for (int k = 0; k < KTOP; k++) {
        int e = topk_i[t * KTOP + k];
        int pos = atomicAdd(&fill[e], 1);
        int s = base[e] + pos;
        slot_tok[s] = t;
        slot_wt[s]  = topk_p[t * KTOP + k];
    }
}

// ======== fused GU: routed (bid<1320) + shared. Tile 128M x 64N, BK=32.
// A: GLDS bf16, 4 buffers, depth-2. B: T14 reg-stage -> bf16 ds_write, 2 buffers.
__global__ __launch_bounds__(256, 2) void gu_all(
    const u16* __restrict__ Xb,
    const float* __restrict__ w_gate, const float* __restrict__ w_up,
    const float* __restrict__ sw_g, const float* __restrict__ sw_u,
    u16* __restrict__ h, u16* __restrict__ hs,
    const int* __restrict__ slot_tok, const float* __restrict__ slot_wt,
    const int* __restrict__ cnt, const int* __restrict__ basea)
{
    __shared__ u16 Asl[4][128 * 32];    // 4 x 8 KB
    __shared__ u16 Bgsl[2][64 * 32];    // 2 x 4 KB
    __shared__ u16 Busl[2][64 * 32];    // 2 x 4 KB  -> 48 KB total

    const int bid = blockIdx.x;
    const bool grouped = bid < NBR_GU;
    const int tid = threadIdx.x, w = tid >> 6, lane = tid & 63;
    const int lm = lane & 15, lk = lane >> 4;
    const int wm0 = (w >> 1) * 64, wn0 = (w & 1) * 32;

    int e = 0, my = 0, nb;
    const float *Wg, *Wu; u16* Hout; int Nout;
    if (grouped) {
        e = bid / 22; nb = bid % 22;
        Wg = w_gate + (size_t)e * ID * HD; Wu = w_up + (size_t)e * ID * HD;
        Hout = h; Nout = ID;
    } else {
        int sid = bid - NBR_GU; my = sid / 88; nb = sid % 88;
        Wg = sw_g; Wu = sw_u; Hout = hs; Nout = SID;
    }
    const int mcnt  = grouped ? cnt[e] : 128;
    const int mbase = grouped ? basea[e] : 0;

    // A: pre-swizzled global source chunk (linear GLDS dest, swizzled read)
    const int aCh = (((lane & 3) ^ ((lane >> 2) & 3) ^ ((lane >> 4) & 3))) << 3;
    // B staging map: row tid>>2 (64 rows), 32B chunk tid&3 (coalesced 128B/row)
    const int brow_s = tid >> 2, bkc = tid & 3;
    const float* pg = Wg + (size_t)(nb * 64 + brow_s) * HD + bkc * 8;
    const float* pu = Wu + (size_t)(nb * 64 + brow_s) * HD + bkc * 8;
    const int bWr = brow_s * 32 + ((bkc ^ ((brow_s >> 1) & 3)) << 3);

    int aOff[4], bOff[2];
    #pragma unroll
    for (int mf = 0; mf < 4; mf++) {
        int r = wm0 + mf * 16 + lm;
        aOff[mf] = r * 32 + ((lk ^ (r & 3) ^ ((r >> 2) & 3)) << 3);
    }
    #pragma unroll
    for (int nf = 0; nf < 2; nf++) {
        int rb = wn0 + nf * 16 + lm;
        bOff[nf] = rb * 32 + ((lk ^ ((rb >> 1) & 3)) << 3);
    }
    const int segA0 = (w * 32) * 32, segA1 = (w * 32 + 16) * 32;
    const int nk = HD >> 5;   // 64 (multiple of 4)

    for (int mt = 0; grouped ? (mt * 128 < mcnt) : (mt == 0); ++mt) {
        const u16* aSrc0; const u16* aSrc1;
        {
            int m0 = w * 32 + (lane >> 2), m1 = m0 + 16;
            int r0, r1;
            if (grouped) {
                int s0 = mbase + mt * 128 + m0, s1 = mbase + mt * 128 + m1;
                r0 = (mt * 128 + m0 < mcnt) ? slot_tok[s0] : slot_tok[mbase];
                r1 = (mt * 128 + m1 < mcnt) ? slot_tok[s1] : slot_tok[mbase];
            } else { r0 = my * 128 + m0; r1 = my * 128 + m1; }
            aSrc0 = Xb + (size_t)r0 * HD + aCh;
            aSrc1 = Xb + (size_t)r1 * HD + aCh;
        }

        f32x4 accG[4][2], accU[4][2];
        #pragma unroll
        for (int mf = 0; mf < 4; mf++)
            #pragma unroll
            for (int nf = 0; nf < 2; nf++) {
                accG[mf][nf] = f32x4{0.f, 0.f, 0.f, 0.f};
                accU[mf][nf] = f32x4{0.f, 0.f, 0.f, 0.f};
            }

        f32x4 ga0, ga1, ua0, ua1;   // B-stage set A (even data steps)
        f32x4 gb0, gb1, ub0, ub1;   // B-stage set B (odd data steps)

#define ISSUE(G0_, G1_, U0_, U1_, AB, KT) do {                                \
        GL4(G0_, pg + (KT)); GL4(G1_, pg + (KT) + 4);                         \
        GL4(U0_, pu + (KT)); GL4(U1_, pu + (KT) + 4);                         \
        GLDS(aSrc0 + (KT), &Asl[AB][segA0]);                                  \
        GLDS(aSrc1 + (KT), &Asl[AB][segA1]);                                  \
    } while (0)

#define WRITEB(G0_, G1_, U0_, U1_, BB) do {                                   \
        *(bf16x8*)&Bgsl[BB][bWr] = cvt8(G0_, G1_);                            \
        *(bf16x8*)&Busl[BB][bWr] = cvt8(U0_, U1_);                            \
    } while (0)

#define COMPSTEP(AB, BB) do {                                                 \
        bf16x8 af[4], bg[2], bu_[2];                                          \
        _Pragma("unroll")                                                     \
        for (int mf = 0; mf < 4; mf++) af[mf] = *(const bf16x8*)&Asl[AB][aOff[mf]]; \
        _Pragma("unroll")                                                     \
        for (int nf = 0; nf < 2; nf++) {                                      \
            bg[nf]  = *(const bf16x8*)&Bgsl[BB][bOff[nf]];                    \
            bu_[nf] = *(const bf16x8*)&Busl[BB][bOff[nf]];                    \
        }                                                                     \
        _Pragma("unroll")                                                     \
        for (int mf = 0; mf < 4; mf++)                                        \
            _Pragma("unroll")                                                 \
            for (int nf = 0; nf < 2; nf++) {                                  \
                accG[mf][nf] = __builtin_amdgcn_mfma_f32_16x16x32_bf16(af[mf], bg[nf],  accG[mf][nf], 0, 0, 0); \
                accU[mf][nf] = __builtin_amdgcn_mfma_f32_16x16x32_bf16(af[mf], bu_[nf], accU[mf][nf], 0, 0, 0); \
            }                                                                 \
    } while (0)

        // prologue: steps 0 (set a, Abuf0) and 1 (set b, Abuf1)
        ISSUE(ga0, ga1, ua0, ua1, 0, 0);
        ISSUE(gb0, gb1, ub0, ub1, 1, 32);
        WAITVM(6);
        WRITEB(ga0, ga1, ua0, ua1, 0);
        LGKMBAR();

        for (int t = 0; t < nk; t += 4) {
            // s = t : comp(A0,B0); issue t+2 -> set a, Abuf2; write t+1 <- set b
            if (t + 2 < nk) { ISSUE(ga0, ga1, ua0, ua1, 2, (t + 2) << 5); COMPSTEP(0, 0); WAITVM(6); }
            else            { COMPSTEP(0, 0); WAITVM(0); }
            if (t + 1 < nk) WRITEB(gb0, gb1, ub0, ub1, 1);
            LGKMBAR();
            // s = t+1 : comp(A1,B1); issue t+3 -> set b, Abuf3; write t+2 <- set a
            if (t + 3 < nk) { ISSUE(gb0, gb1, ub0, ub1, 3, (t + 3) << 5); COMPSTEP(1, 1); WAITVM(6); }
            else            { COMPSTEP(1, 1); WAITVM(0); }
            if (t + 2 < nk) WRITEB(ga0, ga1, ua0, ua1, 0);
            LGKMBAR();
            // s = t+2 : comp(A2,B0); issue t+4 -> set a, Abuf0; write t+3 <- set b
            if (t + 4 < nk) { ISSUE(ga0, ga1, ua0, ua1, 0, (t + 4) << 5); COMPSTEP(2, 0); WAITVM(6); }
            else            { COMPSTEP(2, 0); WAITVM(0); }
            if (t + 3 < nk) WRITEB(gb0, gb1, ub0, ub1, 1);
            LGKMBAR();
            // s = t+3 : comp(A3,B1); issue t+5 -> set b, Abuf1; write t+4 <- set a
            if (t + 5 < nk) { ISSUE(gb0, gb1, ub0, ub1, 1, (t + 5) << 5); COMPSTEP(3, 1); WAITVM(6); }
            else            { COMPSTEP(3, 1); WAITVM(0); }
            if (t + 4 < nk) WRITEB(ga0, ga1, ua0, ua1, 0);
            LGKMBAR();
        }
#undef ISSUE
#undef WRITEB
#undef COMPSTEP

        // epilogue: silu(g)*u*wt -> bf16. D: col=lane&15, row=(lane>>4)*4+reg
        #pragma unroll
        for (int mf = 0; mf < 4; mf++)
            #pragma unroll
            for (int j = 0; j < 4; j++) {
                int m = wm0 + mf * 16 + lk * 4 + j;
                bool valid = grouped ? (mt * 128 + m < mcnt) : true;
                if (valid) {
                    size_t row; float wt;
                    if (grouped) {
                        size_t sl = (size_t)(mbase + mt * 128 + m);
                        row = sl; wt = slot_wt[sl];
                    } else { row = (size_t)(my * 128 + m); wt = 1.f; }
                    #pragma unroll
                    for (int nf = 0; nf < 2; nf++) {
                        int col = nb * 64 + wn0 + nf * 16 + lm;
                        float g = accG[mf][nf][j], u = accU[mf][nf][j];
                        float hv = g / (1.f + __expf(-g)) * u * wt;
                        Hout[row * (size_t)Nout + col] = f2bf(hv);
                    }
                }
            }
    }
}

// ======== fused DOWN: shared (bid<256, K=5632) + routed (K=1408).
// Same pipeline; all-atomicAdd onto pre-zeroed out.
__global__ __launch_bounds__(256, 3) void down_all(
    const u16* __restrict__ h, const u16* __restrict__ hs,
    const float* __restrict__ w_down, const float* __restrict__ sw_d,
    float* __restrict__ outF,
    const int* __restrict__ slot_tok, const float* __restrict__ sgate,
    const int* __restrict__ cnt, const int* __restrict__ basea)
{
    __shared__ u16 Asl[4][128 * 32];    // 32 KB
    __shared__ u16 Bsl[2][64 * 32];     // 8 KB -> 40 KB total

    const int bid = blockIdx.x;
    const bool shared_m = bid < NBS_DN;
    const int tid = threadIdx.x, w = tid >> 6, lane = tid & 63;
    const int lm = lane & 15, lk = lane >> 4;
    const int wm0 = (w >> 1) * 64, wn0 = (w & 1) * 32;

    int e = 0, my = 0, nb, K;
    const u16* Ap; const float* Wp;
    if (shared_m) {
        my = bid / 32; nb = bid % 32; K = SID; Ap = hs; Wp = sw_d;
    } else {
        int rid = bid - NBS_DN; e = rid / 32; nb = rid % 32; K = ID;
        Ap = h; Wp = w_down + (size_t)e * HD * ID;
    }
    const int mcnt  = shared_m ? 128 : cnt[e];
    const int mbase = shared_m ? 0 : basea[e];

    const int aCh = (((lane & 3) ^ ((lane >> 2) & 3) ^ ((lane >> 4) & 3))) << 3;
    const int brow_s = tid >> 2, bkc = tid & 3;
    const float* pb = Wp + (size_t)(nb * 64 + brow_s) * K + bkc * 8;
    const int bWr = brow_s * 32 + ((bkc ^ ((brow_s >> 1) & 3)) << 3);

    int aOff[4], bOff[2];
    #pragma unroll
    for (int mf = 0; mf < 4; mf++) {
        int r = wm0 + mf * 16 + lm;
        aOff[mf] = r * 32 + ((lk ^ (r & 3) ^ ((r >> 2) & 3)) << 3);
    }
    #pragma unroll
    for (int nf = 0; nf < 2; nf++) {
        int rb = wn0 + nf * 16 + lm;
        bOff[nf] = rb * 32 + ((lk ^ ((rb >> 1) & 3)) << 3);
    }
    const int segA0 = (w * 32) * 32, segA1 = (w * 32 + 16) * 32;
    const int nk = K >> 5;   // 176 shared, 44 routed (multiples of 4)

    for (int mt = 0; shared_m ? (mt == 0) : (mt * 128 < mcnt); ++mt) {
        const u16* aSrc0; const u16* aSrc1;
        {
            int m0 = w * 32 + (lane >> 2), m1 = m0 + 16;
            size_t r0, r1;
            if (shared_m) { r0 = (size_t)(my * 128 + m0); r1 = (size_t)(my * 128 + m1); }
            else { r0 = (size_t)(mbase + mt * 128 + m0); r1 = (size_t)(mbase + mt * 128 + m1); } // h padded
            aSrc0 = Ap + r0 * K + aCh;
            aSrc1 = Ap + r1 * K + aCh;
        }

        f32x4 acc[4][2];
        #pragma unroll
        for (int mf = 0; mf < 4; mf++)
            #pragma unroll
            for (int nf = 0; nf < 2; nf++) acc[mf][nf] = f32x4{0.f, 0.f, 0.f, 0.f};

        f32x4 ba0, ba1;   // set A (even data steps)
        f32x4 bb0, bb1;   // set B (odd data steps)

#define ISSUE(B0_, B1_, AB, KT) do {                                          \
        GL4(B0_, pb + (KT)); GL4(B1_, pb + (KT) + 4);                         \
        GLDS(aSrc0 + (KT), &Asl[AB][segA0]);                                  \
        GLDS(aSrc1 + (KT), &Asl[AB][segA1]);                                  \
    } while (0)

#define WRITEB(B0_, B1_, BB) do {                                             \
        *(bf16x8*)&Bsl[BB][bWr] = cvt8(B0_, B1_);                             \
    } while (0)

#define COMPSTEP(AB, BB) do {                                                 \
        bf16x8 af[4], bf_[2];                                                 \
        _Pragma("unroll")                                                     \
        for (int mf = 0; mf < 4; mf++) af[mf] = *(const bf16x8*)&Asl[AB][aOff[mf]]; \
        _Pragma("unroll")                                                     \
        for (int nf = 0; nf < 2; nf++) bf_[nf] = *(const bf16x8*)&Bsl[BB][bOff[nf]]; \
        _Pragma("unroll")                                                     \
        for (int mf = 0; mf < 4; mf++)                                        \
            _Pragma("unroll")                                                 \
            for (int nf = 0; nf < 2; nf++)                                    \
                acc[mf][nf] = __builtin_amdgcn_mfma_f32_16x16x32_bf16(af[mf], bf_[nf], acc[mf][nf], 0, 0, 0); \
    } while (0)

        ISSUE(ba0, ba1, 0, 0);
        ISSUE(bb0, bb1, 1, 32);
        WAITVM(4);
        WRITEB(ba0, ba1, 0);
        LGKMBAR();

        for (int t = 0; t < nk; t += 4) {
            if (t + 2 < nk) { ISSUE(ba0, ba1, 2, (t + 2) << 5); COMPSTEP(0, 0); WAITVM(4); }
            else            { COMPSTEP(0, 0); WAITVM(0); }
            if (t + 1 < nk) WRITEB(bb0, bb1, 1);
            LGKMBAR();
            if (t + 3 < nk) { ISSUE(bb0, bb1, 3, (t + 3) << 5); COMPSTEP(1, 1); WAITVM(4); }
            else            { COMPSTEP(1, 1); WAITVM(0); }
            if (t + 2 < nk) WRITEB(ba0, ba1, 0);
            LGKMBAR();
            if (t + 4 < nk) { ISSUE(ba0, ba1, 0, (t + 4) << 5); COMPSTEP(2, 0); WAITVM(4); }
            else            { COMPSTEP(2, 0); WAITVM(0); }
            if (t + 3 < nk) WRITEB(bb0, bb1, 1);
            LGKMBAR();
            if (t + 5 < nk) { ISSUE(bb0, bb1, 1, (t + 5) << 5); COMPSTEP(3, 1); WAITVM(4); }
            else            { COMPSTEP(3, 1); WAITVM(0); }
            if (t + 4 < nk) WRITEB(ba0, ba1, 0);
            LGKMBAR();
        }
#undef ISSUE
#undef WRITEB
#undef COMPSTEP

        #pragma unroll
        for (int mf = 0; mf < 4; mf++)
            #pragma unroll
            for (int j = 0; j < 4; j++) {
                int m = wm0 + mf * 16 + lk * 4 + j;
                if (mt * 128 + m < mcnt) {
                    int tok; float scale;
                    if (shared_m) { tok = my * 128 + m; scale = sgate[tok]; }
                    else          { tok = slot_tok[mbase + mt * 128 + m]; scale = 1.f; }
                    #pragma unroll
                    for (int nf = 0; nf < 2; nf++) {
                        int col = nb * 64 + wn0 + nf * 16 + lm;
                        atomicAdd(&outF[(size_t)tok * HD + col], scale * acc[mf][nf][j]);
                    }
                }
            }
    }
}

extern "C" void kernel_launch(void* const* d_in, const int* in_sizes, int n_in,
                              void* d_out, int out_size, void* d_ws, size_t ws_size,
                              hipStream_t stream)
{
    const float* x      = (const float*)d_in[0];
    const float* rw     = (const float*)d_in[1];
    const float* w_gate = (const float*)d_in[2];
    const float* w_up   = (const float*)d_in[3];
    const float* w_down = (const float*)d_in[4];
    const float* sw_g   = (const float*)d_in[5];
    const float* sw_u   = (const float*)d_in[6];
    const float* sw_d   = (const float*)d_in[7];
    const float* sgw    = (const float*)d_in[8];
    float* out = (float*)d_out;

    char* ws = (char*)d_ws;
    int*   cnt      = (int*)(ws + 0);
    int*   fill     = (int*)(ws + 256);
    int*   basea    = (int*)(ws + 512);
    float* sgate    = (float*)(ws + 768);
    float* topk_p   = (float*)(ws + 5120);
    int*   topk_i   = (int*)(ws + 21504);
    int*   slot_tok = (int*)(ws + 37888);
    float* slot_wt  = (float*)(ws + 54272);
    u16*   xb = (u16*)(ws + 71680);              // [1024][2048] bf16
    u16*   h  = xb + (size_t)TT * HD;            // [4096+128][1408] bf16 (padded)
    u16*   hs = h + (size_t)(4096 + 128) * ID;   // [1024][5632] bf16

    zero_k<<<1, 128, 0, stream>>>(cnt);                       // cnt + fill
    zeroout_k<<<TT * HD / 1024, 256, 0, stream>>>(out);       // 8.4 MB fast zero
    xcvt_k<<<512, 256, 0, stream>>>(x, xb);
    router_k<<<TT, 64, 0, stream>>>(x, rw, sgw, topk_p, topk_i, cnt, sgate);
    prefix_k<<<1, 64, 0, stream>>>(cnt, basea);
    scatter_k<<<4, 256, 0, stream>>>(topk_p, topk_i, basea, fill, slot_tok, slot_wt);

    gu_all<<<NB_GU, 256, 0, stream>>>(
        xb, w_gate, w_up, sw_g, sw_u, h, hs,
        slot_tok, slot_wt, cnt, basea);

    down_all<<<NB_DN, 256, 0, stream>>>(
        h, hs, w_down, sw_d, out,
        slot_tok, sgate, cnt, basea);
}